// Round 1
// baseline (16741.721 us; speedup 1.0000x reference)
//
#include <hip/hip_runtime.h>
#include <cmath>

// Problem constants (fixed by the reference).
#define SEQ   4096
#define INP   1024
#define HID   1024
#define G4    4096   // 4*HID

// ---------------------------------------------------------------------------
// Kernel 1: xg[t][r] = dot(emb[inputs[t]], W_ih[r]) + b_ih[r] + b_hh[r]
// 64x64 output tile per block, 256 threads, 4x4 micro-tile, fp32 VALU.
// ---------------------------------------------------------------------------
__global__ __launch_bounds__(256) void xg_gemm_kernel(
    const int* __restrict__ inputs,
    const float* __restrict__ emb,
    const float* __restrict__ W_ih,
    const float* __restrict__ b_ih,
    const float* __restrict__ b_hh,
    float* __restrict__ xg)
{
    __shared__ __align__(16) float As[16][68];  // [k][row], +4 pad: 2-way banks (free)
    __shared__ __align__(16) float Bs[16][68];  // [k][col]
    __shared__ int toks[64];

    const int tid = threadIdx.x;
    const int bt = blockIdx.y * 64;   // output rows (timesteps)
    const int br = blockIdx.x * 64;   // output cols (gate rows)

    if (tid < 64) toks[tid] = inputs[bt + tid];
    __syncthreads();

    const int tx = tid & 15;
    const int ty = tid >> 4;
    const int si = tid >> 2;          // staging row/col 0..63
    const int sk = (tid & 3) * 4;     // staging k base 0,4,8,12

    float acc[4][4] = {};

    for (int kk = 0; kk < INP; kk += 16) {
        float4 av = *(const float4*)(emb  + (size_t)toks[si] * INP + kk + sk);
        float4 bv = *(const float4*)(W_ih + (size_t)(br + si) * INP + kk + sk);
        As[sk+0][si] = av.x; As[sk+1][si] = av.y; As[sk+2][si] = av.z; As[sk+3][si] = av.w;
        Bs[sk+0][si] = bv.x; Bs[sk+1][si] = bv.y; Bs[sk+2][si] = bv.z; Bs[sk+3][si] = bv.w;
        __syncthreads();
        #pragma unroll
        for (int k = 0; k < 16; ++k) {
            float4 a = *(const float4*)&As[k][ty * 4];
            float4 b = *(const float4*)&Bs[k][tx * 4];
            float ar[4] = {a.x, a.y, a.z, a.w};
            float brr[4] = {b.x, b.y, b.z, b.w};
            #pragma unroll
            for (int iy = 0; iy < 4; ++iy)
                #pragma unroll
                for (int ix = 0; ix < 4; ++ix)
                    acc[iy][ix] += ar[iy] * brr[ix];
        }
        __syncthreads();
    }

    const int r0 = br + tx * 4;
    float4 bias;
    bias.x = b_ih[r0+0] + b_hh[r0+0];
    bias.y = b_ih[r0+1] + b_hh[r0+1];
    bias.z = b_ih[r0+2] + b_hh[r0+2];
    bias.w = b_ih[r0+3] + b_hh[r0+3];
    #pragma unroll
    for (int iy = 0; iy < 4; ++iy) {
        float4 o;
        o.x = acc[iy][0] + bias.x;
        o.y = acc[iy][1] + bias.y;
        o.z = acc[iy][2] + bias.z;
        o.w = acc[iy][3] + bias.w;
        *(float4*)(xg + (size_t)(bt + ty * 4 + iy) * G4 + r0) = o;
    }
}

// ---------------------------------------------------------------------------
// Kernel 2: persistent cooperative LSTM scan.
// 256 WGs x 256 threads. WG w owns h elements j = 4w..4w+3 (wave v -> element
// 4w+v; 16-lane group q within the wave -> gate row q*1024+j). Each thread
// holds a 64-float chunk of its W_hh row in registers permanently.
// h exchange: hbuf[parity][j] = (tag<<32 | f32bits), device-scope atomics.
//   A buffer entry polled for tag t can only contain {0xAA poison, t-2, t}:
//   a producer writes tag t+2 into that slot only after every WG has fully
//   consumed step t (its own tag-(t+1) write implies that). So tag==t is safe.
// ---------------------------------------------------------------------------
__global__ __launch_bounds__(256) void lstm_kernel(
    const float* __restrict__ xg,
    const float* __restrict__ W_hh,
    const float* __restrict__ h0,
    const float* __restrict__ c0,
    unsigned long long* __restrict__ hbuf,   // 2 * 1024 entries
    float* __restrict__ out)
{
    const int w    = blockIdx.x;   // 0..255
    const int tid  = threadIdx.x;  // 0..255
    const int lane = tid & 63;
    const int wv   = tid >> 6;     // wave 0..3 -> h element j = 4w+wv
    const int q    = lane >> 4;    // gate 0..3 (i,f,g,o)
    const int kc   = lane & 15;    // 64-float h chunk index
    const int j    = w * 4 + wv;
    const int row  = q * HID + j;  // W_hh row for this thread

    // Persistent W_hh fragment: W_hh[row][64*kc .. 64*kc+64) in 64 VGPRs.
    float wreg[64];
    {
        const float* wp = W_hh + (size_t)row * HID + kc * 64;
        #pragma unroll
        for (int m = 0; m < 16; ++m) {
            float4 v = *(const float4*)(wp + 4 * m);
            wreg[4*m+0] = v.x; wreg[4*m+1] = v.y; wreg[4*m+2] = v.z; wreg[4*m+3] = v.w;
        }
    }

    float c = c0[j];  // all 64 lanes of the wave hold the same c (redundant)

    // Publish h0 with tag 0 into parity-0 buffer.
    if (lane == 0) {
        unsigned long long pk = (unsigned long long)__float_as_uint(h0[j]);
        __hip_atomic_store(&hbuf[j], pk, __ATOMIC_RELAXED, __HIP_MEMORY_SCOPE_AGENT);
    }

    __shared__ __align__(16) float hs[16 * 68];  // 16 chunks, stride 68 (pad 4)
    __shared__ float xgs[16];                    // xg values: index 4*q + e

    const int i0  = tid * 4;       // this thread polls entries i0..i0+3
    const int ch0 = i0 >> 6;
    const int ps0 = i0 & 63;
    const int lofs = ch0 * 68 + ps0;

    float a0 = 0.f, a1 = 0.f, a2 = 0.f, a3 = 0.f;  // last-polled h values

    for (int t = 0; t < SEQ; ++t) {
        unsigned long long* buf = hbuf + (size_t)(t & 1) * 1024;

        // Stage this step's xg values (independent of h -> overlaps the poll).
        if (tid < 16) {
            xgs[tid] = xg[(size_t)t * G4 + (tid >> 2) * HID + w * 4 + (tid & 3)];
        }

        // Poll own 4 h entries until tag == t (payload rides in the atomic).
        const unsigned int tg = (unsigned int)t;
        unsigned long long v0, v1, v2, v3;
        for (;;) {
            v0 = __hip_atomic_load(buf + i0 + 0, __ATOMIC_RELAXED, __HIP_MEMORY_SCOPE_AGENT);
            v1 = __hip_atomic_load(buf + i0 + 1, __ATOMIC_RELAXED, __HIP_MEMORY_SCOPE_AGENT);
            v2 = __hip_atomic_load(buf + i0 + 2, __ATOMIC_RELAXED, __HIP_MEMORY_SCOPE_AGENT);
            v3 = __hip_atomic_load(buf + i0 + 3, __ATOMIC_RELAXED, __HIP_MEMORY_SCOPE_AGENT);
            if ((unsigned int)(v0 >> 32) == tg && (unsigned int)(v1 >> 32) == tg &&
                (unsigned int)(v2 >> 32) == tg && (unsigned int)(v3 >> 32) == tg)
                break;
        }
        a0 = __uint_as_float((unsigned int)v0);
        a1 = __uint_as_float((unsigned int)v1);
        a2 = __uint_as_float((unsigned int)v2);
        a3 = __uint_as_float((unsigned int)v3);
        {
            float4 hv4 = {a0, a1, a2, a3};
            *(float4*)&hs[lofs] = hv4;   // single ds_write_b128, 16B aligned
        }
        __syncthreads();

        // dot(wreg, h_chunk): 16 x ds_read_b128, 2-way bank alias (free).
        const float* hp = hs + kc * 68;
        float sx = 0.f, sy = 0.f, sz = 0.f, sw = 0.f;
        #pragma unroll
        for (int m = 0; m < 16; ++m) {
            float4 hv = *(const float4*)(hp + 4 * m);
            sx += wreg[4*m+0] * hv.x;
            sy += wreg[4*m+1] * hv.y;
            sz += wreg[4*m+2] * hv.z;
            sw += wreg[4*m+3] * hv.w;
        }
        float s = (sx + sy) + (sz + sw);
        // reduce across the 16 lanes of this gate group
        s += __shfl_xor(s, 1);
        s += __shfl_xor(s, 2);
        s += __shfl_xor(s, 4);
        s += __shfl_xor(s, 8);
        // gather the 4 gate sums (lanes 0,16,32,48) to every lane
        float gi = __shfl(s, 0);
        float gf = __shfl(s, 16);
        float gg = __shfl(s, 32);
        float go = __shfl(s, 48);
        gi += xgs[0 + wv];
        gf += xgs[4 + wv];
        gg += xgs[8 + wv];
        go += xgs[12 + wv];

        float ig = 1.0f / (1.0f + __expf(-gi));
        float fg = 1.0f / (1.0f + __expf(-gf));
        float gc = tanhf(gg);
        float og = 1.0f / (1.0f + __expf(-go));
        c = fg * c + ig * gc;
        float h = og * tanhf(c);

        if (lane == 0) {
            unsigned long long pk =
                ((unsigned long long)(unsigned int)(t + 1) << 32) |
                (unsigned long long)__float_as_uint(h);
            __hip_atomic_store(hbuf + (size_t)((t + 1) & 1) * 1024 + j, pk,
                               __ATOMIC_RELAXED, __HIP_MEMORY_SCOPE_AGENT);
        }
        __syncthreads();  // protect hs/xgs from next iteration's writes
    }

    // ------------------- final log_softmax (WG 0 only) -------------------
    if (w != 0) return;

    {
        const unsigned int tg = (unsigned int)SEQ;  // tag 4096, parity 0
        unsigned long long v0, v1, v2, v3;
        for (;;) {
            v0 = __hip_atomic_load(hbuf + i0 + 0, __ATOMIC_RELAXED, __HIP_MEMORY_SCOPE_AGENT);
            v1 = __hip_atomic_load(hbuf + i0 + 1, __ATOMIC_RELAXED, __HIP_MEMORY_SCOPE_AGENT);
            v2 = __hip_atomic_load(hbuf + i0 + 2, __ATOMIC_RELAXED, __HIP_MEMORY_SCOPE_AGENT);
            v3 = __hip_atomic_load(hbuf + i0 + 3, __ATOMIC_RELAXED, __HIP_MEMORY_SCOPE_AGENT);
            if ((unsigned int)(v0 >> 32) == tg && (unsigned int)(v1 >> 32) == tg &&
                (unsigned int)(v2 >> 32) == tg && (unsigned int)(v3 >> 32) == tg)
                break;
        }
        a0 = __uint_as_float((unsigned int)v0);
        a1 = __uint_as_float((unsigned int)v1);
        a2 = __uint_as_float((unsigned int)v2);
        a3 = __uint_as_float((unsigned int)v3);
    }

    __shared__ float rmax[4];
    __shared__ float rsum[4];

    float lm = fmaxf(fmaxf(a0, a1), fmaxf(a2, a3));
    #pragma unroll
    for (int d = 1; d < 64; d <<= 1) lm = fmaxf(lm, __shfl_xor(lm, d));
    if (lane == 0) rmax[wv] = lm;
    __syncthreads();
    const float gm = fmaxf(fmaxf(rmax[0], rmax[1]), fmaxf(rmax[2], rmax[3]));

    float ls = expf(a0 - gm) + expf(a1 - gm) + expf(a2 - gm) + expf(a3 - gm);
    #pragma unroll
    for (int d = 1; d < 64; d <<= 1) ls += __shfl_xor(ls, d);
    if (lane == 0) rsum[wv] = ls;
    __syncthreads();
    const float lse = gm + logf(rsum[0] + rsum[1] + rsum[2] + rsum[3]);

    float4 o;
    o.x = a0 - lse; o.y = a1 - lse; o.z = a2 - lse; o.w = a3 - lse;
    *(float4*)(out + i0) = o;
}

// ---------------------------------------------------------------------------
extern "C" void kernel_launch(void* const* d_in, const int* in_sizes, int n_in,
                              void* d_out, int out_size, void* d_ws, size_t ws_size,
                              hipStream_t stream)
{
    const int*   inputs = (const int*)d_in[0];
    const float* emb    = (const float*)d_in[1];
    const float* W_ih   = (const float*)d_in[2];
    const float* W_hh   = (const float*)d_in[3];
    const float* b_ih   = (const float*)d_in[4];
    const float* b_hh   = (const float*)d_in[5];
    const float* h0     = (const float*)d_in[6];
    const float* c0     = (const float*)d_in[7];
    float* out = (float*)d_out;

    // Workspace layout: [0, 64MB) xg ; [64MB, +16KB) hbuf (2*1024 u64).
    float* xg = (float*)d_ws;
    unsigned long long* hbuf =
        (unsigned long long*)((char*)d_ws + (size_t)SEQ * G4 * sizeof(float));

    dim3 g1(G4 / 64, SEQ / 64), b1(256);
    hipLaunchKernelGGL(xg_gemm_kernel, g1, b1, 0, stream,
                       inputs, emb, W_ih, b_ih, b_hh, xg);

    void* args[] = { (void*)&xg, (void*)&W_hh, (void*)&h0, (void*)&c0,
                     (void*)&hbuf, (void*)&out };
    hipLaunchCooperativeKernel((void*)lstm_kernel, dim3(256), dim3(256),
                               args, 0u, stream);
}

// Round 2
// 14443.866 us; speedup vs baseline: 1.1591x; 1.1591x over previous
//
#include <hip/hip_runtime.h>
#include <cmath>

// Problem constants (fixed by the reference).
#define SEQ   4096
#define INP   1024
#define HID   1024
#define G4    4096   // 4*HID

// ---------------------------------------------------------------------------
// Kernel 1: xg[t][r] = dot(emb[inputs[t]], W_ih[r]) + b_ih[r] + b_hh[r]
// 64x64 output tile per block, 256 threads, 4x4 micro-tile, fp32 VALU.
// ---------------------------------------------------------------------------
__global__ __launch_bounds__(256) void xg_gemm_kernel(
    const int* __restrict__ inputs,
    const float* __restrict__ emb,
    const float* __restrict__ W_ih,
    const float* __restrict__ b_ih,
    const float* __restrict__ b_hh,
    float* __restrict__ xg)
{
    __shared__ __align__(16) float As[16][68];
    __shared__ __align__(16) float Bs[16][68];
    __shared__ int toks[64];

    const int tid = threadIdx.x;
    const int bt = blockIdx.y * 64;
    const int br = blockIdx.x * 64;

    if (tid < 64) toks[tid] = inputs[bt + tid];
    __syncthreads();

    const int tx = tid & 15;
    const int ty = tid >> 4;
    const int si = tid >> 2;
    const int sk = (tid & 3) * 4;

    float acc[4][4] = {};

    for (int kk = 0; kk < INP; kk += 16) {
        float4 av = *(const float4*)(emb  + (size_t)toks[si] * INP + kk + sk);
        float4 bv = *(const float4*)(W_ih + (size_t)(br + si) * INP + kk + sk);
        As[sk+0][si] = av.x; As[sk+1][si] = av.y; As[sk+2][si] = av.z; As[sk+3][si] = av.w;
        Bs[sk+0][si] = bv.x; Bs[sk+1][si] = bv.y; Bs[sk+2][si] = bv.z; Bs[sk+3][si] = bv.w;
        __syncthreads();
        #pragma unroll
        for (int k = 0; k < 16; ++k) {
            float4 a = *(const float4*)&As[k][ty * 4];
            float4 b = *(const float4*)&Bs[k][tx * 4];
            float ar[4] = {a.x, a.y, a.z, a.w};
            float brr[4] = {b.x, b.y, b.z, b.w};
            #pragma unroll
            for (int iy = 0; iy < 4; ++iy)
                #pragma unroll
                for (int ix = 0; ix < 4; ++ix)
                    acc[iy][ix] += ar[iy] * brr[ix];
        }
        __syncthreads();
    }

    const int r0 = br + tx * 4;
    float4 bias;
    bias.x = b_ih[r0+0] + b_hh[r0+0];
    bias.y = b_ih[r0+1] + b_hh[r0+1];
    bias.z = b_ih[r0+2] + b_hh[r0+2];
    bias.w = b_ih[r0+3] + b_hh[r0+3];
    #pragma unroll
    for (int iy = 0; iy < 4; ++iy) {
        float4 o;
        o.x = acc[iy][0] + bias.x;
        o.y = acc[iy][1] + bias.y;
        o.z = acc[iy][2] + bias.z;
        o.w = acc[iy][3] + bias.w;
        *(float4*)(xg + (size_t)(bt + ty * 4 + iy) * G4 + r0) = o;
    }
}

// ---------------------------------------------------------------------------
// Fast saturating activations (threshold is lenient; clamp prevents inf/inf).
// ---------------------------------------------------------------------------
__device__ __forceinline__ float fast_sigmoid(float x) {
    x = fminf(fmaxf(x, -30.f), 30.f);
    return __builtin_amdgcn_rcpf(1.0f + __expf(-x));
}
__device__ __forceinline__ float fast_tanh(float x) {
    x = fminf(fmaxf(x, -15.f), 15.f);
    float e = __expf(2.0f * x);
    return (e - 1.0f) * __builtin_amdgcn_rcpf(e + 1.0f);
}

// ---------------------------------------------------------------------------
// Kernel 2: persistent cooperative LSTM scan.
// 64 WGs x 1024 threads. Wave wv (0..15) of WG w owns h element j = w*16+wv.
// Within a wave: 16-lane group q = gate (i,f,g,o), kc = 64-float chunk of h.
// Each thread holds W_hh[q*1024+j][kc*64 .. +64) permanently in 64 VGPRs.
//
// h exchange: hbuf[parity][e] = (tag<<32 | f32bits), agent-scope atomics.
// Thread tid polls exactly ONE entry (e = tid) -> 8 KB/WG/poll-round, 64 WGs
// (4x less poll traffic than R1's 256 WGs x 4 entries). Slot-reuse safety:
// tag t+2 is written only after the producer passed step t+1's barrier, which
// required every WG (each owns >=1 polled... every WG polls all 1024 slots)
// to have fully consumed tag t. Poison 0xAAAAAAAA never matches a valid tag.
//
// One __syncthreads per step: hs/xgs are parity double-buffered; the barrier
// at step t+1 orders all step-t reads before any step-t+2 writes.
// ---------------------------------------------------------------------------
__global__ __launch_bounds__(1024) void lstm_kernel(
    const float* __restrict__ xg,
    const float* __restrict__ W_hh,
    const float* __restrict__ h0,
    const float* __restrict__ c0,
    unsigned long long* __restrict__ hbuf,   // 2 * 1024 entries
    float* __restrict__ out)
{
    const int w    = blockIdx.x;   // 0..63
    const int tid  = threadIdx.x;  // 0..1023
    const int lane = tid & 63;
    const int wv   = tid >> 6;     // wave 0..15 -> h element j = w*16+wv
    const int q    = lane >> 4;    // gate 0..3 (i,f,g,o)
    const int kc   = lane & 15;    // 64-float h chunk index
    const int j    = w * 16 + wv;
    const int row  = q * HID + j;

    // Persistent W_hh fragment in 64 VGPRs.
    float wreg[64];
    {
        const float* wp = W_hh + (size_t)row * HID + kc * 64;
        #pragma unroll
        for (int m = 0; m < 16; ++m) {
            float4 v = *(const float4*)(wp + 4 * m);
            wreg[4*m+0] = v.x; wreg[4*m+1] = v.y; wreg[4*m+2] = v.z; wreg[4*m+3] = v.w;
        }
    }

    float c = c0[j];

    // Publish h0 with tag 0 (parity 0).
    if (lane == 0) {
        unsigned long long pk = (unsigned long long)__float_as_uint(h0[j]);
        __hip_atomic_store(&hbuf[j], pk, __ATOMIC_RELAXED, __HIP_MEMORY_SCOPE_AGENT);
    }

    __shared__ __align__(16) float hs[2][16 * 68];  // parity-double-buffered h
    __shared__ float xgs[2][64];                    // gate q, element wv -> [q*16+wv]

    const int lofs = (tid >> 6) * 68 + (tid & 63);  // LDS slot for polled elem
    const bool hasx = (tid < 64);
    const size_t xgofs = (size_t)(tid >> 4) * HID + w * 16 + (tid & 15);

    for (int t = 0; t < SEQ; ++t) {
        const int par = t & 1;
        unsigned long long* buf = hbuf + (size_t)par * 1024;

        // Issue the xg load before the poll so its latency hides under it.
        float xv = 0.f;
        if (hasx) xv = xg[(size_t)t * G4 + xgofs];

        // Poll this thread's single h entry until tag == t.
        const unsigned int tg = (unsigned int)t;
        unsigned long long v;
        do {
            v = __hip_atomic_load(buf + tid, __ATOMIC_RELAXED, __HIP_MEMORY_SCOPE_AGENT);
        } while ((unsigned int)(v >> 32) != tg);

        hs[par][lofs] = __uint_as_float((unsigned int)v);
        if (hasx) xgs[par][tid] = xv;
        __syncthreads();

        // dot(wreg, h chunk kc): 16 x ds_read_b128 (2-way bank alias = free).
        const float* hp = hs[par] + kc * 68;
        float sx = 0.f, sy = 0.f, sz = 0.f, sw = 0.f;
        #pragma unroll
        for (int m = 0; m < 16; ++m) {
            float4 hv = *(const float4*)(hp + 4 * m);
            sx += wreg[4*m+0] * hv.x;
            sy += wreg[4*m+1] * hv.y;
            sz += wreg[4*m+2] * hv.z;
            sw += wreg[4*m+3] * hv.w;
        }
        float s = (sx + sy) + (sz + sw);
        s += __shfl_xor(s, 1);
        s += __shfl_xor(s, 2);
        s += __shfl_xor(s, 4);
        s += __shfl_xor(s, 8);
        float gi = __shfl(s, 0)  + xgs[par][ 0 + wv];
        float gf = __shfl(s, 16) + xgs[par][16 + wv];
        float gg = __shfl(s, 32) + xgs[par][32 + wv];
        float go = __shfl(s, 48) + xgs[par][48 + wv];

        float ig = fast_sigmoid(gi);
        float fg = fast_sigmoid(gf);
        float gc = fast_tanh(gg);
        float og = fast_sigmoid(go);
        c = fg * c + ig * gc;
        float h = og * fast_tanh(c);

        if (lane == 0) {
            unsigned long long pk =
                ((unsigned long long)(unsigned int)(t + 1) << 32) |
                (unsigned long long)__float_as_uint(h);
            __hip_atomic_store(hbuf + (size_t)((t + 1) & 1) * 1024 + j, pk,
                               __ATOMIC_RELAXED, __HIP_MEMORY_SCOPE_AGENT);
        }
        // No trailing barrier: hs/xgs are parity-buffered; next write to this
        // parity happens after the NEXT step's barrier, which orders it after
        // every thread's reads this step.
    }

    // ------------------- final log_softmax (WG 0 only) -------------------
    if (w != 0) return;

    float a;
    {
        const unsigned int tg = (unsigned int)SEQ;  // SEQ even -> parity 0
        unsigned long long v;
        do {
            v = __hip_atomic_load(hbuf + tid, __ATOMIC_RELAXED, __HIP_MEMORY_SCOPE_AGENT);
        } while ((unsigned int)(v >> 32) != tg);
        a = __uint_as_float((unsigned int)v);
    }

    __shared__ float rmax[16];
    __shared__ float rsum[16];

    float lm = a;
    #pragma unroll
    for (int d = 1; d < 64; d <<= 1) lm = fmaxf(lm, __shfl_xor(lm, d));
    if (lane == 0) rmax[wv] = lm;
    __syncthreads();
    float gm = rmax[0];
    #pragma unroll
    for (int i = 1; i < 16; ++i) gm = fmaxf(gm, rmax[i]);

    float ls = expf(a - gm);
    #pragma unroll
    for (int d = 1; d < 64; d <<= 1) ls += __shfl_xor(ls, d);
    if (lane == 0) rsum[wv] = ls;
    __syncthreads();
    float tot = rsum[0];
    #pragma unroll
    for (int i = 1; i < 16; ++i) tot += rsum[i];
    const float lse = gm + logf(tot);

    out[tid] = a - lse;
}

// ---------------------------------------------------------------------------
extern "C" void kernel_launch(void* const* d_in, const int* in_sizes, int n_in,
                              void* d_out, int out_size, void* d_ws, size_t ws_size,
                              hipStream_t stream)
{
    const int*   inputs = (const int*)d_in[0];
    const float* emb    = (const float*)d_in[1];
    const float* W_ih   = (const float*)d_in[2];
    const float* W_hh   = (const float*)d_in[3];
    const float* b_ih   = (const float*)d_in[4];
    const float* b_hh   = (const float*)d_in[5];
    const float* h0     = (const float*)d_in[6];
    const float* c0     = (const float*)d_in[7];
    float* out = (float*)d_out;

    // Workspace layout: [0, 64MB) xg ; [64MB, +16KB) hbuf (2*1024 u64).
    float* xg = (float*)d_ws;
    unsigned long long* hbuf =
        (unsigned long long*)((char*)d_ws + (size_t)SEQ * G4 * sizeof(float));

    dim3 g1(G4 / 64, SEQ / 64), b1(256);
    hipLaunchKernelGGL(xg_gemm_kernel, g1, b1, 0, stream,
                       inputs, emb, W_ih, b_ih, b_hh, xg);

    void* args[] = { (void*)&xg, (void*)&W_hh, (void*)&h0, (void*)&c0,
                     (void*)&hbuf, (void*)&out };
    hipLaunchCooperativeKernel((void*)lstm_kernel, dim3(64), dim3(1024),
                               args, 0u, stream);
}